// Round 3
// 181.027 us; speedup vs baseline: 1.0133x; 1.0133x over previous
//
#include <hip/hip_runtime.h>

#define IMG_W 512
#define IMG_H 512
#define N_IMG 48            // 16 batch * 3 channels
#define TILE_W 64
#define TILE_H 32
#define RAD 5
#define XROWS 48            // 42 halo rows padded to 3 m-tiles of 16
#define XCOLS 84            // R9: was 80. Row stride 168B -> read start-bank 10*n15%32
                            // (16 distinct) vs 8*n15%32 (4 distinct, 4-8-way conflict).
                            // Cols 80..83 are never written/read (pad only).
#define YTROWS 56           // R9: was 48. Row stride 112B: 16B-aligned (b128 reads stay
                            // legal) and 28*n15%32 gives 8 start banks ~2-way (free).
#define NBX (IMG_W / TILE_W)   // 8
#define NBY (IMG_H / TILE_H)   // 16

typedef float f32x4v __attribute__((ext_vector_type(4)));
typedef short bf16x8 __attribute__((ext_vector_type(8)));
typedef short bf16x4 __attribute__((ext_vector_type(4)));

// R11 BISECT: v_cvt_pk_bf16_f32 inline asm REMOVED everywhere — it is the one
// component common to both NaN rounds (R9/R10) absent from the passing R8
// kernel, and the only one whose HW behavior I can't audit from first
// principles. Restored R8-proven RNE packing below.
__device__ inline short bf16r(float a) {
    unsigned int u = __float_as_uint(a);
    u = (u + 0x7fffu + ((u >> 16) & 1u)) >> 16;
    return (short)u;
}
__device__ inline unsigned int bf16pair(float a, float b) {
    return (unsigned int)(unsigned short)bf16r(a)
         | ((unsigned int)(unsigned short)bf16r(b) << 16);
}

// R10/R11: fragment build via closed form (no workspace, no ssum loop, no divide):
//   w(d) = exp(-(d-5)^2/4.5)/ssum = exp2(-(d-5)^2 * log2e/4.5) * (1/ssum)
// log2e/4.5 = 0.32059890, 1/ssum = 0.26601246 folded at compile time.
// 16 v_exp + ~120 VALU per thread vs R8's 43 expf + ~500 VALU. Values match
// R8's weights to <=1 bf16 ulp (threshold has 2.5x headroom over R8's absmax).
__device__ inline bf16x8 make_frag(int dbase) {
    bf16x8 f;
    #pragma unroll
    for (int j = 0; j < 8; ++j) {
        const int d = dbase + j;
        const float x = (float)(d - 5);
        const float w = exp2f(-0.32059890f * x * x) * 0.26601246f;
        f[j] = bf16r((d >= 0 && d <= 10) ? w : 0.f);
    }
    return f;
}

__global__ void ssim_zero_acc(double* acc) {
    if (threadIdx.x == 0) acc[0] = 0.0;
}

// NOTE 1 (R3/R4 vs R5): NO __threadfence / fold-in finalize. Per-block
// agent-scope fence forces XCD-L2 writeback 6144x/dispatch; halo re-reads
// fall L2->L3 and dur triples. Separate finalize kernel is free.
// NOTE 2 (R6): launch_bounds min-waves stays 4. (256,6) made the allocator
// spill ~67MB to scratch. LDS (40.4KB) caps us at 4 blocks/CU anyway.
// NOTE 3 (R8): both 11-tap convs run on MFMA: data in A (k-contiguous b64/b128
// from LDS), banded Gaussian weights in B (B[k][n]=wt[k-n-c], closed-form in
// registers). C/D layout (col=lane&15,row=q*4+reg) writes 4 row-consecutive
// values of one col = b64 into transposed Y -> the transpose the V-pass
// A-fragments need is free.
__global__ __launch_bounds__(256, 4)
void ssim_main(const float* __restrict__ pred, const float* __restrict__ targ,
               double* __restrict__ acc)
{
    __shared__ __align__(16) union {
        unsigned short X [5][XROWS][XCOLS];    // [arr][halo row][ci], ci = imgcol - col0 + 8
        unsigned short YT[5][TILE_W][YTROWS];  // [arr][tile col][halo row]
    } sh;
    __shared__ float wave_part[4];

    const int tid  = threadIdx.x;
    const int lane = tid & 63;
    const int wv   = tid >> 6;     // wave 0..3
    const int n15  = lane & 15;
    const int q    = lane >> 4;    // 0..3

    // B fragments (weights), one per conv. Lane holds B[k][n], n=lane&15,
    // k=q*8+j. Hconv: tap d = k - n - 3 (k-window starts 3 cols left of the
    // leftmost tap of out col 0). Vconv: d = k - n (n-tile1 reuses the same
    // fragment via a K-window starting at row 16).
    const bf16x8 Bh = make_frag(q * 8 - n15 - 3);
    const bf16x8 Bv = make_frag(q * 8 - n15);

    const int col0 = blockIdx.x * TILE_W;
    const int row0 = blockIdx.y * TILE_H;
    const bool edge = (blockIdx.x == 0) || (blockIdx.x == NBX - 1);
    const long img = blockIdx.z;
    const float* __restrict__ p = pred + img * (long)(IMG_H * IMG_W);
    const float* __restrict__ t = targ + img * (long)(IMG_H * IMG_W);

    // ---- Phase 0: stage {p,t,pp,tt,pt} bf16 into X, zero outside image.
    // Every data element of X cols 0..79 is written (finite) — MFMA reads that
    // footprint and 0-weight x Inf/NaN garbage would poison accumulators.
    for (int idx = tid; idx < XROWS * 20; idx += 256) {   // 960 items
        const int r = idx / 20;
        const int g = idx - r * 20;
        const int gr  = row0 - RAD + r;
        const int gcb = col0 - 8 + 4 * g;
        float pv[4] = {0.f, 0.f, 0.f, 0.f};
        float tv[4] = {0.f, 0.f, 0.f, 0.f};
        if (gr >= 0 && gr < IMG_H) {
            const float* __restrict__ prow = p + (long)gr * IMG_W;
            const float* __restrict__ trow = t + (long)gr * IMG_W;
            if (!edge || (gcb >= 0 && gcb + 4 <= IMG_W)) {
                const float4 a = *(const float4*)&prow[gcb];
                const float4 b = *(const float4*)&trow[gcb];
                pv[0] = a.x; pv[1] = a.y; pv[2] = a.z; pv[3] = a.w;
                tv[0] = b.x; tv[1] = b.y; tv[2] = b.z; tv[3] = b.w;
            } else {
                #pragma unroll
                for (int e = 0; e < 4; ++e) {
                    const int c = gcb + e;
                    if (c >= 0 && c < IMG_W) { pv[e] = prow[c]; tv[e] = trow[c]; }
                }
            }
        }
        *(uint2*)&sh.X[0][r][4 * g] = make_uint2(bf16pair(pv[0], pv[1]), bf16pair(pv[2], pv[3]));
        *(uint2*)&sh.X[1][r][4 * g] = make_uint2(bf16pair(tv[0], tv[1]), bf16pair(tv[2], tv[3]));
        *(uint2*)&sh.X[2][r][4 * g] = make_uint2(bf16pair(pv[0]*pv[0], pv[1]*pv[1]),
                                                 bf16pair(pv[2]*pv[2], pv[3]*pv[3]));
        *(uint2*)&sh.X[3][r][4 * g] = make_uint2(bf16pair(tv[0]*tv[0], tv[1]*tv[1]),
                                                 bf16pair(tv[2]*tv[2], tv[3]*tv[3]));
        *(uint2*)&sh.X[4][r][4 * g] = make_uint2(bf16pair(pv[0]*tv[0], pv[1]*tv[1]),
                                                 bf16pair(pv[2]*tv[2], pv[3]*tv[3]));
    }
    __syncthreads();

    // ---- MFMA pass 1: horizontal conv. Wave wv owns out-col tile wv.
    // A[m][k] = X[mt*16+m][wv*16+k]; D[m][n] = Y[mt*16+m][outcol wv*16+n].
    // Lane gets 4 row-consecutive values of one col -> pack -> held in regs
    // until X is fully consumed (barrier), then b64 into transposed YT.
    // R9: A-read as 2x ds_read_b64 — 168B rows are 8-aligned only; the b64 pair
    // at 16-distinct start banks beats an 8-way-conflicted b128.
    uint2 yreg[15];
    {
        const f32x4v cz = {0.f, 0.f, 0.f, 0.f};
        int i = 0;
        #pragma unroll
        for (int a = 0; a < 5; ++a) {
            #pragma unroll
            for (int mt = 0; mt < 3; ++mt) {
                const bf16x4 alo = *(const bf16x4*)&sh.X[a][mt * 16 + n15][wv * 16 + 8 * q];
                const bf16x4 ahi = *(const bf16x4*)&sh.X[a][mt * 16 + n15][wv * 16 + 8 * q + 4];
                const bf16x8 A = {alo[0], alo[1], alo[2], alo[3],
                                  ahi[0], ahi[1], ahi[2], ahi[3]};
                const f32x4v c = __builtin_amdgcn_mfma_f32_16x16x32_bf16(A, Bh, cz, 0, 0, 0);
                yreg[i++] = make_uint2(bf16pair(c[0], c[1]), bf16pair(c[2], c[3]));
            }
        }
    }
    __syncthreads();   // all X reads complete; union space becomes YT
    {
        int i = 0;
        #pragma unroll
        for (int a = 0; a < 5; ++a)
            #pragma unroll
            for (int mt = 0; mt < 3; ++mt)
                *(uint2*)&sh.YT[a][wv * 16 + n15][mt * 16 + 4 * q] = yreg[i++];
    }
    __syncthreads();

    // ---- MFMA pass 2: vertical conv. Wave wv owns image-col tile wv.
    // A[m][k] = YT[col wv*16+m][nt*16+k] (K-window rows nt*16..+31, band fits
    // for both n-tiles with the same Bv). D[m][n]: lane gets out row
    // nt*16+n15, cols wv*16+q*4+{0..3} for the 5 arrays. 112B rows: b128 ok.
    f32x4v accv[2][5];
    {
        const f32x4v cz = {0.f, 0.f, 0.f, 0.f};
        #pragma unroll
        for (int nt = 0; nt < 2; ++nt)
            #pragma unroll
            for (int a = 0; a < 5; ++a) {
                const bf16x8 A = *(const bf16x8*)&sh.YT[a][wv * 16 + n15][nt * 16 + 8 * q];
                accv[nt][a] = __builtin_amdgcn_mfma_f32_16x16x32_bf16(A, Bv, cz, 0, 0, 0);
            }
    }

    // ---- SSIM on 8 pixels/lane (2 n-tiles x 4 cols), fp32 ----
    float lsum = 0.f;
    #pragma unroll
    for (int nt = 0; nt < 2; ++nt) {
        const f32x4v m1 = accv[nt][0], m2 = accv[nt][1];
        const f32x4v epp = accv[nt][2], ett = accv[nt][3], ept = accv[nt][4];
        const f32x4v m1s = m1 * m1, m2s = m2 * m2, m12 = m1 * m2;
        const f32x4v num = (2.f * m12 + 1e-4f) * (2.f * (ept - m12) + 9e-4f);
        const f32x4v den = (m1s + m2s + 1e-4f) * ((epp - m1s) + (ett - m2s) + 9e-4f);
        lsum += num[0] * __builtin_amdgcn_rcpf(den[0]);
        lsum += num[1] * __builtin_amdgcn_rcpf(den[1]);
        lsum += num[2] * __builtin_amdgcn_rcpf(den[2]);
        lsum += num[3] * __builtin_amdgcn_rcpf(den[3]);
    }

    // ---- Block reduction -> one double atomic per block ----
    #pragma unroll
    for (int off = 32; off > 0; off >>= 1)
        lsum += __shfl_down(lsum, off, 64);
    if (lane == 0) wave_part[wv] = lsum;
    __syncthreads();
    if (tid == 0) {
        const float bs = wave_part[0] + wave_part[1] + wave_part[2] + wave_part[3];
        atomicAdd(acc, (double)bs);
    }
}

__global__ void ssim_final(const double* __restrict__ acc, float* __restrict__ out) {
    if (threadIdx.x == 0) {
        const double n = (double)N_IMG * (double)IMG_H * (double)IMG_W;
        out[0] = (float)(1.0 - acc[0] / n);
    }
}

extern "C" void kernel_launch(void* const* d_in, const int* in_sizes, int n_in,
                              void* d_out, int out_size, void* d_ws, size_t ws_size,
                              hipStream_t stream) {
    const float* pred = (const float*)d_in[0];
    const float* targ = (const float*)d_in[1];
    float* out  = (float*)d_out;
    double* acc = (double*)d_ws;

    hipLaunchKernelGGL(ssim_zero_acc, dim3(1), dim3(1), 0, stream, acc);
    dim3 grid(NBX, NBY, N_IMG);   // (8, 16, 48)
    hipLaunchKernelGGL(ssim_main, grid, dim3(256), 0, stream, pred, targ, acc);
    hipLaunchKernelGGL(ssim_final, dim3(1), dim3(1), 0, stream, acc, out);
}